// Round 3
// baseline (386.170 us; speedup 1.0000x reference)
//
#include <hip/hip_runtime.h>
#include <hip/hip_bf16.h>
#include <stdint.h>

typedef __bf16 bf16x8 __attribute__((ext_vector_type(8)));
typedef float  f32x4  __attribute__((ext_vector_type(4)));
typedef uint32_t u32x4 __attribute__((ext_vector_type(4)));
typedef unsigned long long u64;

#define M_NODES 100000
#define K_IN    256
#define N_OUT   128
#define N_EDGE  1600000

#define SB         256                      // nodes per src bucket (64 KB bf16)
#define NB         ((M_NODES + SB - 1) / SB) // 391 buckets
#define SCATTER_CH 2048

// ---------------------------------------------------------------------------
// Stage 1: h[M,N] = in[M,K] @ w[K,N]. Unchanged from R1 (B panel in VGPRs,
// grid-stride tiles, guard-free hot path). Not yet visible in top-5 counters.
// ---------------------------------------------------------------------------
template <bool FULL>
__device__ __forceinline__ void gemm_tile(
    const float* __restrict__ in, float* __restrict__ h,
    __hip_bfloat16* __restrict__ hmir,
    const bf16x8 (&bfrag)[8][2], const int m0, const int lr, const int q,
    const int nb)
{
    f32x4 acc[4][2];
    #pragma unroll
    for (int mt = 0; mt < 4; ++mt)
        #pragma unroll
        for (int nt = 0; nt < 2; ++nt)
            acc[mt][nt] = f32x4{0.f, 0.f, 0.f, 0.f};

    #pragma unroll
    for (int k8 = 0; k8 < 8; ++k8) {
        const int ka = k8 * 32 + q * 8;
        bf16x8 afrag[4];
        #pragma unroll
        for (int mt = 0; mt < 4; ++mt) {
            const int row = m0 + mt * 16 + lr;
            if (FULL || row < M_NODES) {
                const float* ap = in + (size_t)row * K_IN + ka;
                const f32x4 a0 = *(const f32x4*)ap;
                const f32x4 a1 = *(const f32x4*)(ap + 4);
                #pragma unroll
                for (int j = 0; j < 4; ++j) {
                    afrag[mt][j]     = (__bf16)a0[j];
                    afrag[mt][4 + j] = (__bf16)a1[j];
                }
            } else {
                #pragma unroll
                for (int j = 0; j < 8; ++j) afrag[mt][j] = (__bf16)0.f;
            }
        }
        #pragma unroll
        for (int mt = 0; mt < 4; ++mt)
            #pragma unroll
            for (int nt = 0; nt < 2; ++nt)
                acc[mt][nt] = __builtin_amdgcn_mfma_f32_16x16x32_bf16(
                    afrag[mt], bfrag[k8][nt], acc[mt][nt], 0, 0, 0);
    }

    #pragma unroll
    for (int mt = 0; mt < 4; ++mt) {
        const int rb = m0 + mt * 16 + q * 4;
        if (!FULL && rb >= M_NODES) continue;
        #pragma unroll
        for (int nt = 0; nt < 2; ++nt) {
            const int col = nb + nt * 16 + lr;
            #pragma unroll
            for (int r = 0; r < 4; ++r) {
                const float v = acc[mt][nt][r];
                __builtin_nontemporal_store(v, h + (size_t)(rb + r) * N_OUT + col);
                hmir[(size_t)(rb + r) * N_OUT + col] = __float2bfloat16(v);
            }
        }
    }
}

__global__ __launch_bounds__(256) void gemm_h_mfma(
    const float* __restrict__ in,
    const float* __restrict__ w,
    float* __restrict__ h,
    __hip_bfloat16* __restrict__ hmir)
{
    const int lane = threadIdx.x & 63;
    const int wave = threadIdx.x >> 6;
    const int nb   = wave * 32;
    const int lr   = lane & 15;
    const int q    = lane >> 4;

    bf16x8 bfrag[8][2];
    #pragma unroll
    for (int k8 = 0; k8 < 8; ++k8) {
        const int ka = k8 * 32 + q * 8;
        #pragma unroll
        for (int nt = 0; nt < 2; ++nt) {
            const int col = nb + nt * 16 + lr;
            #pragma unroll
            for (int j = 0; j < 8; ++j)
                bfrag[k8][nt][j] = (__bf16)w[(size_t)(ka + j) * N_OUT + col];
        }
    }

    const int ntiles = (M_NODES + 63) / 64;
    const int nfull  = M_NODES / 64;
    for (int t = blockIdx.x; t < ntiles; t += gridDim.x) {
        const int m0 = t * 64;
        if (t < nfull) gemm_tile<true >(in, h, hmir, bfrag, m0, lr, q, nb);
        else           gemm_tile<false>(in, h, hmir, bfrag, m0, lr, q, nb);
    }
}

// int64 edge indices < 1e5: every high word is 0. int32: odd words random.
__device__ inline int detect_i64(const uint32_t* p) {
    return __popcll(__ballot(p[2 * (threadIdx.x & 63) + 1] == 0u)) >= 60;
}

// ---------------------------------------------------------------------------
// R3 prepass: bucket edges by src>>8 (391 buckets of 256 rows = 64 KB LDS
// window). rec[pos] = src_local(9b) | dst<<9  (u32). perm[e] = pos (coalesced)
// enables the coalesced-output + reorder scheme that fixes R2's NT-scatter
// writeback amplification (WRITE 68.5 MB -> ~6.5 MB predicted).
// ---------------------------------------------------------------------------
__global__ __launch_bounds__(256) void edge_hist(
    const uint32_t* __restrict__ edge_raw, int E, uint32_t* __restrict__ hist)
{
    __shared__ uint32_t lh[NB];
    for (int i = threadIdx.x; i < NB; i += 256) lh[i] = 0;
    const int e64 = detect_i64(edge_raw);
    __syncthreads();
    const int stride = gridDim.x * 256;
    for (int e = blockIdx.x * 256 + threadIdx.x; e < E; e += stride) {
        const int src = e64 ? (int)edge_raw[2 * (size_t)e]
                            : ((const int*)edge_raw)[e];
        atomicAdd(&lh[src >> 8], 1u);
    }
    __syncthreads();
    for (int i = threadIdx.x; i < NB; i += 256)
        if (lh[i]) atomicAdd(&hist[i], lh[i]);
}

// ctrl (uint32): [0:NB) hist, [NB:2NB) start, [2NB:3NB) cursor
__global__ void bucket_prefix(uint32_t* __restrict__ ctrl)
{
    if (threadIdx.x == 0) {
        uint32_t s = 0;
        for (int b = 0; b < NB; ++b) {
            ctrl[NB + b]     = s;
            ctrl[2 * NB + b] = s;
            s += ctrl[b];
        }
    }
}

__global__ __launch_bounds__(256) void edge_scatter(
    const uint32_t* __restrict__ edge_raw, int E,
    uint32_t* __restrict__ cursor,           // ctrl + 2*NB
    uint32_t* __restrict__ rec,
    uint32_t* __restrict__ perm)
{
    const int e64 = detect_i64(edge_raw);
    __shared__ uint32_t cnt[NB], basev[NB], cur[NB];
    for (int i = threadIdx.x; i < NB; i += 256) { cnt[i] = 0; cur[i] = 0; }
    __syncthreads();

    const int e0 = blockIdx.x * SCATTER_CH;
    int src[8], dst[8], bb[8];
    #pragma unroll
    for (int u = 0; u < 8; ++u) {
        const int e = e0 + u * 256 + threadIdx.x;
        if (e < E) {
            if (e64) {
                src[u] = (int)edge_raw[2 * (size_t)e];
                dst[u] = (int)edge_raw[2 * ((size_t)E + e)];
            } else {
                src[u] = ((const int*)edge_raw)[e];
                dst[u] = ((const int*)edge_raw)[(size_t)E + e];
            }
            bb[u] = src[u] >> 8;
            atomicAdd(&cnt[bb[u]], 1u);
        } else bb[u] = -1;
    }
    __syncthreads();
    for (int i = threadIdx.x; i < NB; i += 256)
        if (cnt[i]) basev[i] = atomicAdd(&cursor[i], cnt[i]);
    __syncthreads();
    #pragma unroll
    for (int u = 0; u < 8; ++u) {
        if (bb[u] >= 0) {
            const int e = e0 + u * 256 + threadIdx.x;
            const uint32_t pos = basev[bb[u]] + atomicAdd(&cur[bb[u]], 1u);
            rec[pos]  = (uint32_t)(src[u] & (SB - 1)) | ((uint32_t)dst[u] << 9);
            perm[e]   = pos;                 // coalesced in e
        }
    }
}

// ---------------------------------------------------------------------------
// R3 compute: block = (bucket, half). Src window staged in LDS (64 KB,
// conflict-free ds_read_b128 pattern); dst gathered from L2/LLC (plain loads
// so L2 caches them); rec nt-loaded; output written COALESCED to tmp in
// bucket order (plain full-line stores).
// ---------------------------------------------------------------------------
__global__ __launch_bounds__(256) void edge_compute_lds(
    const __hip_bfloat16* __restrict__ hm,
    const uint32_t* __restrict__ rec,
    const uint32_t* __restrict__ ctrl,
    const float* __restrict__ a,
    float* __restrict__ tmp)
{
    __shared__ __bf16 sm[SB * N_OUT];        // 65536 B
    const int b    = blockIdx.x >> 1;
    const int half = blockIdx.x & 1;
    const int t    = threadIdx.x;

    const int rbase = b * SB;
    const int nrows = (M_NODES - rbase < SB) ? (M_NODES - rbase) : SB;

    {   // stage src window: 16 iters x 256 thr x 16 B = 64 KB
        const u32x4* gsrc = (const u32x4*)(hm + (size_t)rbase * N_OUT);
        u32x4* lds = (u32x4*)sm;
        #pragma unroll
        for (int i = 0; i < 16; ++i) {
            const int idx = i * 256 + t;     // 16B-unit index; row = idx>>4
            if ((idx >> 4) < nrows) lds[idx] = gsrc[idx];
        }
    }
    __syncthreads();

    const uint32_t n  = ctrl[b];
    const uint32_t st = ctrl[NB + b];
    const uint32_t lo = half ? (n + 1) / 2 : 0;
    const uint32_t hi = half ? n : (n + 1) / 2;

    const int s   = t & 15;
    const int grp = t >> 4;
    const f32x4 a0 = *(const f32x4*)(a + s * 8);
    const f32x4 a1 = *(const f32x4*)(a + s * 8 + 4);
    const __bf16* hb = (const __bf16*)hm;
    const uint32_t sentinel = (uint32_t)rbase << 9;  // lsrc=0, dst=rbase (safe)

    for (uint32_t off = lo + (uint32_t)grp * 8; off < hi; off += 16 * 8) {
        const uint32_t rem = hi - off;
        const int nv = rem < 8u ? (int)rem : 8;

        uint32_t r[8];
        #pragma unroll
        for (int u = 0; u < 8; ++u)
            r[u] = (u < nv) ? __builtin_nontemporal_load(rec + st + off + u)
                            : sentinel;

        bf16x8 hs[8], hd[8];
        #pragma unroll
        for (int u = 0; u < 8; ++u) {
            const int lsrc = (int)(r[u] & 0x1FF);
            const int dst  = (int)(r[u] >> 9);
            hs[u] = *(const bf16x8*)(sm + (size_t)lsrc * N_OUT + s * 8);
            hd[u] = *(const bf16x8*)(hb + (size_t)dst * N_OUT + s * 8);
        }

        #pragma unroll
        for (int u = 0; u < 8; ++u) {
            float sum = 0.f;
            #pragma unroll
            for (int i = 0; i < 4; ++i)
                sum += fabsf((float)hs[u][i] - (float)hd[u][i]) * a0[i];
            #pragma unroll
            for (int i = 0; i < 4; ++i)
                sum += fabsf((float)hs[u][4 + i] - (float)hd[u][4 + i]) * a1[i];
            sum += __shfl_xor(sum, 1, 64);
            sum += __shfl_xor(sum, 2, 64);
            sum += __shfl_xor(sum, 4, 64);
            sum += __shfl_xor(sum, 8, 64);
            if (s == 0 && u < nv)
                tmp[st + off + u] = fmaxf(sum, 0.f);   // coalesced across groups
        }
    }
}

// ew[e] = tmp[perm[e]] — coalesced read/write; gather hits LLC-resident tmp.
__global__ __launch_bounds__(256) void edge_reorder(
    const float* __restrict__ tmp,
    const uint32_t* __restrict__ perm,
    float* __restrict__ ew, int E)
{
    const int e0 = (blockIdx.x * 256 + threadIdx.x) * 4;
    if (e0 + 3 < E) {
        const u32x4 p = *(const u32x4*)(perm + e0);
        f32x4 v;
        v[0] = tmp[p[0]]; v[1] = tmp[p[1]]; v[2] = tmp[p[2]]; v[3] = tmp[p[3]];
        *(f32x4*)(ew + e0) = v;
    } else {
        for (int e = e0; e < E; ++e) ew[e] = tmp[perm[e]];
    }
}

// ---------------------------------------------------------------------------
// Fallbacks (ws too small): R1's proven kernels.
// ---------------------------------------------------------------------------
__global__ __launch_bounds__(256) void edge_kernel_bf16(
    const __hip_bfloat16* __restrict__ hm,
    const uint32_t* __restrict__ edge_raw,
    const float* __restrict__ a,
    float* __restrict__ ew,
    int E)
{
    const int e64 = detect_i64(edge_raw);
    const int s  = threadIdx.x & 15;
    const int g  = (int)((blockIdx.x * 256 + threadIdx.x) >> 4);
    const int e0 = g * 4;
    if (e0 >= E) return;

    const __bf16* hb = (const __bf16*)hm;
    const f32x4 a0 = *(const f32x4*)(a + s * 8);
    const f32x4 a1 = *(const f32x4*)(a + s * 8 + 4);

    if (e0 + 3 < E) {
        int srcs[4], dsts[4];
        if (e64) {
            const uint4 s01 = *(const uint4*)(edge_raw + 2 * (size_t)e0);
            const uint4 s23 = *(const uint4*)(edge_raw + 2 * (size_t)e0 + 4);
            const uint4 d01 = *(const uint4*)(edge_raw + 2 * ((size_t)E + e0));
            const uint4 d23 = *(const uint4*)(edge_raw + 2 * ((size_t)E + e0) + 4);
            srcs[0] = (int)s01.x; srcs[1] = (int)s01.z;
            srcs[2] = (int)s23.x; srcs[3] = (int)s23.z;
            dsts[0] = (int)d01.x; dsts[1] = (int)d01.z;
            dsts[2] = (int)d23.x; dsts[3] = (int)d23.z;
        } else {
            const int4 sv = *(const int4*)((const int*)edge_raw + e0);
            const int4 dv = *(const int4*)((const int*)edge_raw + (size_t)E + e0);
            srcs[0] = sv.x; srcs[1] = sv.y; srcs[2] = sv.z; srcs[3] = sv.w;
            dsts[0] = dv.x; dsts[1] = dv.y; dsts[2] = dv.z; dsts[3] = dv.w;
        }

        bf16x8 hs[4], hd[4];
        #pragma unroll
        for (int u = 0; u < 4; ++u) {
            hs[u] = *(const bf16x8*)(hb + (size_t)srcs[u] * N_OUT + s * 8);
            hd[u] = *(const bf16x8*)(hb + (size_t)dsts[u] * N_OUT + s * 8);
        }

        f32x4 rr;
        #pragma unroll
        for (int u = 0; u < 4; ++u) {
            float sum = 0.f;
            #pragma unroll
            for (int i = 0; i < 4; ++i)
                sum += fabsf((float)hs[u][i] - (float)hd[u][i]) * a0[i];
            #pragma unroll
            for (int i = 0; i < 4; ++i)
                sum += fabsf((float)hs[u][4 + i] - (float)hd[u][4 + i]) * a1[i];
            sum += __shfl_xor(sum, 1, 64);
            sum += __shfl_xor(sum, 2, 64);
            sum += __shfl_xor(sum, 4, 64);
            sum += __shfl_xor(sum, 8, 64);
            rr[u] = fmaxf(sum, 0.f);
        }
        if (s == 0) *(f32x4*)(ew + e0) = rr;
    } else {
        for (int e = e0; e < E; ++e) {
            int src, dst;
            if (e64) {
                src = (int)edge_raw[2 * (size_t)e];
                dst = (int)edge_raw[2 * ((size_t)E + e)];
            } else {
                const int* e32 = (const int*)edge_raw;
                src = e32[e];
                dst = e32[(size_t)E + e];
            }
            const bf16x8 hs = *(const bf16x8*)(hb + (size_t)src * N_OUT + s * 8);
            const bf16x8 hd = *(const bf16x8*)(hb + (size_t)dst * N_OUT + s * 8);
            float sum = 0.f;
            #pragma unroll
            for (int i = 0; i < 4; ++i)
                sum += fabsf((float)hs[i] - (float)hd[i]) * a0[i];
            #pragma unroll
            for (int i = 0; i < 4; ++i)
                sum += fabsf((float)hs[4 + i] - (float)hd[4 + i]) * a1[i];
            sum += __shfl_xor(sum, 1, 64);
            sum += __shfl_xor(sum, 2, 64);
            sum += __shfl_xor(sum, 4, 64);
            sum += __shfl_xor(sum, 8, 64);
            if (s == 0) ew[e] = fmaxf(sum, 0.f);
        }
    }
}

__global__ __launch_bounds__(256) void edge_kernel_f32(
    const float* __restrict__ h,
    const uint32_t* __restrict__ edge_raw,
    const float* __restrict__ a,
    float* __restrict__ ew,
    int E)
{
    const int e64 = detect_i64(edge_raw);
    const int s = threadIdx.x & 15;
    const int e = (int)((blockIdx.x * 256 + threadIdx.x) >> 4);
    if (e >= E) return;

    int src, dst;
    if (e64) {
        src = (int)edge_raw[2 * (size_t)e];
        dst = (int)edge_raw[2 * ((size_t)E + e)];
    } else {
        const int* e32 = (const int*)edge_raw;
        src = e32[e];
        dst = e32[(size_t)E + e];
    }

    const f32x4 s0 = *(const f32x4*)(h + (size_t)src * N_OUT + s * 8);
    const f32x4 s1 = *(const f32x4*)(h + (size_t)src * N_OUT + s * 8 + 4);
    const f32x4 d0 = *(const f32x4*)(h + (size_t)dst * N_OUT + s * 8);
    const f32x4 d1 = *(const f32x4*)(h + (size_t)dst * N_OUT + s * 8 + 4);
    const f32x4 a0 = *(const f32x4*)(a + s * 8);
    const f32x4 a1 = *(const f32x4*)(a + s * 8 + 4);

    float sum = 0.f;
    #pragma unroll
    for (int i = 0; i < 4; ++i) sum += fabsf(s0[i] - d0[i]) * a0[i];
    #pragma unroll
    for (int i = 0; i < 4; ++i) sum += fabsf(s1[i] - d1[i]) * a1[i];

    sum += __shfl_xor(sum, 1, 64);
    sum += __shfl_xor(sum, 2, 64);
    sum += __shfl_xor(sum, 4, 64);
    sum += __shfl_xor(sum, 8, 64);

    if (s == 0) ew[e] = fmaxf(sum, 0.f);
}

extern "C" void kernel_launch(void* const* d_in, const int* in_sizes, int n_in,
                              void* d_out, int out_size, void* d_ws, size_t ws_size,
                              hipStream_t stream) {
    const float*    in   = (const float*)d_in[0];
    const uint32_t* edge = (const uint32_t*)d_in[1];
    const float*    w    = (const float*)d_in[2];
    const float*    a    = (const float*)d_in[3];

    float* h  = (float*)d_out;
    float* ew = h + (size_t)M_NODES * N_OUT;

    // ws layout: [mirror 25.6M][ctrl 8K][rec 6.4M][perm 6.4M][tmp 6.4M] = 44.8 MB
    const size_t mirror_bytes = (size_t)M_NODES * N_OUT * sizeof(__hip_bfloat16);
    const size_t ctrl_off = mirror_bytes;
    const size_t rec_off  = ctrl_off + 8192;
    const size_t perm_off = rec_off + (size_t)N_EDGE * 4;
    const size_t tmp_off  = perm_off + (size_t)N_EDGE * 4;
    const size_t need     = tmp_off + (size_t)N_EDGE * 4;

    __hip_bfloat16* hmir = (ws_size >= mirror_bytes) ? (__hip_bfloat16*)d_ws : nullptr;

    if (hmir && ws_size >= need) {
        uint32_t* ctrl = (uint32_t*)((char*)d_ws + ctrl_off);
        uint32_t* rec  = (uint32_t*)((char*)d_ws + rec_off);
        uint32_t* perm = (uint32_t*)((char*)d_ws + perm_off);
        float*    tmp  = (float*)((char*)d_ws + tmp_off);

        hipMemsetAsync(ctrl, 0, 8192, stream);
        edge_hist<<<dim3(512), dim3(256), 0, stream>>>(edge, N_EDGE, ctrl);
        bucket_prefix<<<dim3(1), dim3(64), 0, stream>>>(ctrl);
        edge_scatter<<<dim3((N_EDGE + SCATTER_CH - 1) / SCATTER_CH), dim3(256),
                       0, stream>>>(edge, N_EDGE, ctrl + 2 * NB, rec, perm);
        gemm_h_mfma<<<dim3(512), dim3(256), 0, stream>>>(in, w, h, hmir);
        edge_compute_lds<<<dim3(NB * 2), dim3(256), 0, stream>>>(
            hmir, rec, ctrl, a, tmp);
        edge_reorder<<<dim3((N_EDGE / 4 + 255) / 256), dim3(256), 0, stream>>>(
            tmp, perm, ew, N_EDGE);
    } else if (hmir) {
        gemm_h_mfma<<<dim3(512), dim3(256), 0, stream>>>(in, w, h, hmir);
        const int egroups = (N_EDGE + 3) / 4;
        const int eblocks = (egroups * 16 + 255) / 256;
        edge_kernel_bf16<<<dim3(eblocks), dim3(256), 0, stream>>>(
            hmir, edge, a, ew, N_EDGE);
    } else {
        gemm_h_mfma<<<dim3(512), dim3(256), 0, stream>>>(
            in, w, h, (__hip_bfloat16*)d_ws);
        const int eblocks = (N_EDGE * 16 + 255) / 256;
        edge_kernel_f32<<<dim3(eblocks), dim3(256), 0, stream>>>(
            h, edge, a, ew, N_EDGE);
    }
}

// Round 4
// 363.610 us; speedup vs baseline: 1.0620x; 1.0620x over previous
//
#include <hip/hip_runtime.h>
#include <hip/hip_bf16.h>
#include <stdint.h>

typedef __bf16 bf16x8 __attribute__((ext_vector_type(8)));
typedef float  f32x4  __attribute__((ext_vector_type(4)));
typedef uint32_t u32x4 __attribute__((ext_vector_type(4)));
typedef unsigned long long u64;

#define M_NODES 100000
#define K_IN    256
#define N_OUT   128
#define N_EDGE  1600000

#define SB         128                        // nodes per src bucket (32 KB bf16 LDS)
#define NB         ((M_NODES + SB - 1) / SB)  // 782 buckets
#define SCATTER_CH 8192                       // edges per scatter block (full-line chunks)

// ---------------------------------------------------------------------------
// Stage 1: h[M,N] = in[M,K] @ w[K,N]. Unchanged (B panel in VGPRs, grid-stride
// tiles, guard-free hot path). Expected to surface in top-5 this round.
// ---------------------------------------------------------------------------
template <bool FULL>
__device__ __forceinline__ void gemm_tile(
    const float* __restrict__ in, float* __restrict__ h,
    __hip_bfloat16* __restrict__ hmir,
    const bf16x8 (&bfrag)[8][2], const int m0, const int lr, const int q,
    const int nb)
{
    f32x4 acc[4][2];
    #pragma unroll
    for (int mt = 0; mt < 4; ++mt)
        #pragma unroll
        for (int nt = 0; nt < 2; ++nt)
            acc[mt][nt] = f32x4{0.f, 0.f, 0.f, 0.f};

    #pragma unroll
    for (int k8 = 0; k8 < 8; ++k8) {
        const int ka = k8 * 32 + q * 8;
        bf16x8 afrag[4];
        #pragma unroll
        for (int mt = 0; mt < 4; ++mt) {
            const int row = m0 + mt * 16 + lr;
            if (FULL || row < M_NODES) {
                const float* ap = in + (size_t)row * K_IN + ka;
                const f32x4 a0 = *(const f32x4*)ap;
                const f32x4 a1 = *(const f32x4*)(ap + 4);
                #pragma unroll
                for (int j = 0; j < 4; ++j) {
                    afrag[mt][j]     = (__bf16)a0[j];
                    afrag[mt][4 + j] = (__bf16)a1[j];
                }
            } else {
                #pragma unroll
                for (int j = 0; j < 8; ++j) afrag[mt][j] = (__bf16)0.f;
            }
        }
        #pragma unroll
        for (int mt = 0; mt < 4; ++mt)
            #pragma unroll
            for (int nt = 0; nt < 2; ++nt)
                acc[mt][nt] = __builtin_amdgcn_mfma_f32_16x16x32_bf16(
                    afrag[mt], bfrag[k8][nt], acc[mt][nt], 0, 0, 0);
    }

    #pragma unroll
    for (int mt = 0; mt < 4; ++mt) {
        const int rb = m0 + mt * 16 + q * 4;
        if (!FULL && rb >= M_NODES) continue;
        #pragma unroll
        for (int nt = 0; nt < 2; ++nt) {
            const int col = nb + nt * 16 + lr;
            #pragma unroll
            for (int r = 0; r < 4; ++r) {
                const float v = acc[mt][nt][r];
                __builtin_nontemporal_store(v, h + (size_t)(rb + r) * N_OUT + col);
                hmir[(size_t)(rb + r) * N_OUT + col] = __float2bfloat16(v);
            }
        }
    }
}

__global__ __launch_bounds__(256) void gemm_h_mfma(
    const float* __restrict__ in,
    const float* __restrict__ w,
    float* __restrict__ h,
    __hip_bfloat16* __restrict__ hmir)
{
    const int lane = threadIdx.x & 63;
    const int wave = threadIdx.x >> 6;
    const int nb   = wave * 32;
    const int lr   = lane & 15;
    const int q    = lane >> 4;

    bf16x8 bfrag[8][2];
    #pragma unroll
    for (int k8 = 0; k8 < 8; ++k8) {
        const int ka = k8 * 32 + q * 8;
        #pragma unroll
        for (int nt = 0; nt < 2; ++nt) {
            const int col = nb + nt * 16 + lr;
            #pragma unroll
            for (int j = 0; j < 8; ++j)
                bfrag[k8][nt][j] = (__bf16)w[(size_t)(ka + j) * N_OUT + col];
        }
    }

    const int ntiles = (M_NODES + 63) / 64;
    const int nfull  = M_NODES / 64;
    for (int t = blockIdx.x; t < ntiles; t += gridDim.x) {
        const int m0 = t * 64;
        if (t < nfull) gemm_tile<true >(in, h, hmir, bfrag, m0, lr, q, nb);
        else           gemm_tile<false>(in, h, hmir, bfrag, m0, lr, q, nb);
    }
}

// int64 edge indices < 1e5: every high word is 0. int32: odd words random.
__device__ inline int detect_i64(const uint32_t* p) {
    return __popcll(__ballot(p[2 * (threadIdx.x & 63) + 1] == 0u)) >= 60;
}

// ---------------------------------------------------------------------------
// R4 prepass: bucket edges by src>>7 (782 buckets of 128 rows = 32 KB LDS
// window). rec[pos] = lsrc(7b) | dst<<7 (17b) | eid<<24 (21b)  -> u64.
// eid in the record lets compute scatter ew directly (reorder pass deleted).
// ---------------------------------------------------------------------------
__global__ __launch_bounds__(256) void edge_hist(
    const uint32_t* __restrict__ edge_raw, int E, uint32_t* __restrict__ hist)
{
    __shared__ uint32_t lh[NB];
    for (int i = threadIdx.x; i < NB; i += 256) lh[i] = 0;
    const int e64 = detect_i64(edge_raw);
    __syncthreads();
    const int stride = gridDim.x * 256;
    for (int e = blockIdx.x * 256 + threadIdx.x; e < E; e += stride) {
        const int src = e64 ? (int)edge_raw[2 * (size_t)e]
                            : ((const int*)edge_raw)[e];
        atomicAdd(&lh[src >> 7], 1u);
    }
    __syncthreads();
    for (int i = threadIdx.x; i < NB; i += 256)
        if (lh[i]) atomicAdd(&hist[i], lh[i]);
}

// ctrl (uint32): [0:NB) hist, [NB:2NB) start, [2NB:3NB) cursor
__global__ void bucket_prefix(uint32_t* __restrict__ ctrl)
{
    if (threadIdx.x == 0) {
        uint32_t s = 0;
        for (int b = 0; b < NB; ++b) {
            ctrl[NB + b]     = s;
            ctrl[2 * NB + b] = s;
            s += ctrl[b];
        }
    }
}

// Two-pass scatter: 8192 edges/block -> ~10.5 edges/bucket/block -> rec chunks
// of ~84 B (u64) per bucket, mostly full lines (vs R3's ~5-word shreds).
__global__ __launch_bounds__(256) void edge_scatter(
    const uint32_t* __restrict__ edge_raw, int E,
    uint32_t* __restrict__ cursor,           // ctrl + 2*NB
    u64* __restrict__ rec)
{
    const int e64 = detect_i64(edge_raw);
    __shared__ uint32_t cnt[NB], basev[NB], cur[NB];
    for (int i = threadIdx.x; i < NB; i += 256) { cnt[i] = 0; cur[i] = 0; }
    __syncthreads();

    const int e0 = blockIdx.x * SCATTER_CH;
    // pass A: count (src words only; L2-hot for pass B)
    #pragma unroll 4
    for (int u = 0; u < SCATTER_CH / 256; ++u) {
        const int e = e0 + u * 256 + threadIdx.x;
        if (e < E) {
            const int src = e64 ? (int)edge_raw[2 * (size_t)e]
                                : ((const int*)edge_raw)[e];
            atomicAdd(&cnt[src >> 7], 1u);
        }
    }
    __syncthreads();
    for (int i = threadIdx.x; i < NB; i += 256)
        if (cnt[i]) basev[i] = atomicAdd(&cursor[i], cnt[i]);
    __syncthreads();
    // pass B: write records
    #pragma unroll 4
    for (int u = 0; u < SCATTER_CH / 256; ++u) {
        const int e = e0 + u * 256 + threadIdx.x;
        if (e < E) {
            int src, dst;
            if (e64) {
                src = (int)edge_raw[2 * (size_t)e];
                dst = (int)edge_raw[2 * ((size_t)E + e)];
            } else {
                src = ((const int*)edge_raw)[e];
                dst = ((const int*)edge_raw)[(size_t)E + e];
            }
            const int b = src >> 7;
            const uint32_t pos = basev[b] + atomicAdd(&cur[b], 1u);
            rec[pos] = (u64)(uint32_t)(src & (SB - 1))
                     | ((u64)(uint32_t)dst << 7)
                     | ((u64)(uint32_t)e << 24);
        }
    }
}

// ---------------------------------------------------------------------------
// R4 compute: one block per bucket; 32 KB LDS src window (4-5 blocks/CU,
// ~12 waves/CU vs R3's 5). dst gathered plain from L2/LLC; ew scattered
// DIRECTLY with plain stores (R2's failure was NT; plain lets L2 combine).
// ---------------------------------------------------------------------------
__global__ __launch_bounds__(256) void edge_compute_lds(
    const __hip_bfloat16* __restrict__ hm,
    const u64* __restrict__ rec,
    const uint32_t* __restrict__ ctrl,
    const float* __restrict__ a,
    float* __restrict__ ew)
{
    __shared__ __bf16 sm[SB * N_OUT];        // 32768 B
    const int b = blockIdx.x;
    const int t = threadIdx.x;

    const int rbase = b * SB;
    const int nrows = (M_NODES - rbase < SB) ? (M_NODES - rbase) : SB;

    {   // stage src window: 8 iters x 256 thr x 16 B = 32 KB (row = idx>>4)
        const u32x4* gsrc = (const u32x4*)(hm + (size_t)rbase * N_OUT);
        u32x4* lds = (u32x4*)sm;
        #pragma unroll
        for (int i = 0; i < 8; ++i) {
            const int idx = i * 256 + t;
            if ((idx >> 4) < nrows) lds[idx] = gsrc[idx];
        }
    }
    __syncthreads();

    const uint32_t n  = ctrl[b];
    const uint32_t st = ctrl[NB + b];

    const int s   = t & 15;
    const int grp = t >> 4;
    const f32x4 a0 = *(const f32x4*)(a + s * 8);
    const f32x4 a1 = *(const f32x4*)(a + s * 8 + 4);
    const __bf16* hb = (const __bf16*)hm;

    for (uint32_t off = (uint32_t)grp * 8; off < n; off += 16 * 8) {
        const uint32_t rem = n - off;
        const int nv = rem < 8u ? (int)rem : 8;

        u64 r[8];
        #pragma unroll
        for (int u = 0; u < 8; ++u)
            r[u] = (u < nv) ? __builtin_nontemporal_load(rec + st + off + u)
                            : 0ull;           // lsrc=0,dst=0: safe; store guarded

        bf16x8 hs[8], hd[8];
        #pragma unroll
        for (int u = 0; u < 8; ++u) {
            const int lsrc = (int)(r[u] & (SB - 1));
            const int dst  = (int)((r[u] >> 7) & 0x1FFFF);
            hs[u] = *(const bf16x8*)(sm + (size_t)lsrc * N_OUT + s * 8);
            hd[u] = *(const bf16x8*)(hb + (size_t)dst * N_OUT + s * 8);
        }

        #pragma unroll
        for (int u = 0; u < 8; ++u) {
            float sum = 0.f;
            #pragma unroll
            for (int i = 0; i < 4; ++i)
                sum += fabsf((float)hs[u][i] - (float)hd[u][i]) * a0[i];
            #pragma unroll
            for (int i = 0; i < 4; ++i)
                sum += fabsf((float)hs[u][4 + i] - (float)hd[u][4 + i]) * a1[i];
            sum += __shfl_xor(sum, 1, 64);
            sum += __shfl_xor(sum, 2, 64);
            sum += __shfl_xor(sum, 4, 64);
            sum += __shfl_xor(sum, 8, 64);
            if (s == 0 && u < nv)
                ew[(uint32_t)(r[u] >> 24)] = fmaxf(sum, 0.f);  // plain scatter
        }
    }
}

// ---------------------------------------------------------------------------
// Fallbacks (ws too small): R1's proven kernels.
// ---------------------------------------------------------------------------
__global__ __launch_bounds__(256) void edge_kernel_bf16(
    const __hip_bfloat16* __restrict__ hm,
    const uint32_t* __restrict__ edge_raw,
    const float* __restrict__ a,
    float* __restrict__ ew,
    int E)
{
    const int e64 = detect_i64(edge_raw);
    const int s  = threadIdx.x & 15;
    const int g  = (int)((blockIdx.x * 256 + threadIdx.x) >> 4);
    const int e0 = g * 4;
    if (e0 >= E) return;

    const __bf16* hb = (const __bf16*)hm;
    const f32x4 a0 = *(const f32x4*)(a + s * 8);
    const f32x4 a1 = *(const f32x4*)(a + s * 8 + 4);

    if (e0 + 3 < E) {
        int srcs[4], dsts[4];
        if (e64) {
            const uint4 s01 = *(const uint4*)(edge_raw + 2 * (size_t)e0);
            const uint4 s23 = *(const uint4*)(edge_raw + 2 * (size_t)e0 + 4);
            const uint4 d01 = *(const uint4*)(edge_raw + 2 * ((size_t)E + e0));
            const uint4 d23 = *(const uint4*)(edge_raw + 2 * ((size_t)E + e0) + 4);
            srcs[0] = (int)s01.x; srcs[1] = (int)s01.z;
            srcs[2] = (int)s23.x; srcs[3] = (int)s23.z;
            dsts[0] = (int)d01.x; dsts[1] = (int)d01.z;
            dsts[2] = (int)d23.x; dsts[3] = (int)d23.z;
        } else {
            const int4 sv = *(const int4*)((const int*)edge_raw + e0);
            const int4 dv = *(const int4*)((const int*)edge_raw + (size_t)E + e0);
            srcs[0] = sv.x; srcs[1] = sv.y; srcs[2] = sv.z; srcs[3] = sv.w;
            dsts[0] = dv.x; dsts[1] = dv.y; dsts[2] = dv.z; dsts[3] = dv.w;
        }

        bf16x8 hs[4], hd[4];
        #pragma unroll
        for (int u = 0; u < 4; ++u) {
            hs[u] = *(const bf16x8*)(hb + (size_t)srcs[u] * N_OUT + s * 8);
            hd[u] = *(const bf16x8*)(hb + (size_t)dsts[u] * N_OUT + s * 8);
        }

        f32x4 rr;
        #pragma unroll
        for (int u = 0; u < 4; ++u) {
            float sum = 0.f;
            #pragma unroll
            for (int i = 0; i < 4; ++i)
                sum += fabsf((float)hs[u][i] - (float)hd[u][i]) * a0[i];
            #pragma unroll
            for (int i = 0; i < 4; ++i)
                sum += fabsf((float)hs[u][4 + i] - (float)hd[u][4 + i]) * a1[i];
            sum += __shfl_xor(sum, 1, 64);
            sum += __shfl_xor(sum, 2, 64);
            sum += __shfl_xor(sum, 4, 64);
            sum += __shfl_xor(sum, 8, 64);
            rr[u] = fmaxf(sum, 0.f);
        }
        if (s == 0) *(f32x4*)(ew + e0) = rr;
    } else {
        for (int e = e0; e < E; ++e) {
            int src, dst;
            if (e64) {
                src = (int)edge_raw[2 * (size_t)e];
                dst = (int)edge_raw[2 * ((size_t)E + e)];
            } else {
                const int* e32 = (const int*)edge_raw;
                src = e32[e];
                dst = e32[(size_t)E + e];
            }
            const bf16x8 hs = *(const bf16x8*)(hb + (size_t)src * N_OUT + s * 8);
            const bf16x8 hd = *(const bf16x8*)(hb + (size_t)dst * N_OUT + s * 8);
            float sum = 0.f;
            #pragma unroll
            for (int i = 0; i < 4; ++i)
                sum += fabsf((float)hs[i] - (float)hd[i]) * a0[i];
            #pragma unroll
            for (int i = 0; i < 4; ++i)
                sum += fabsf((float)hs[4 + i] - (float)hd[4 + i]) * a1[i];
            sum += __shfl_xor(sum, 1, 64);
            sum += __shfl_xor(sum, 2, 64);
            sum += __shfl_xor(sum, 4, 64);
            sum += __shfl_xor(sum, 8, 64);
            if (s == 0) ew[e] = fmaxf(sum, 0.f);
        }
    }
}

__global__ __launch_bounds__(256) void edge_kernel_f32(
    const float* __restrict__ h,
    const uint32_t* __restrict__ edge_raw,
    const float* __restrict__ a,
    float* __restrict__ ew,
    int E)
{
    const int e64 = detect_i64(edge_raw);
    const int s = threadIdx.x & 15;
    const int e = (int)((blockIdx.x * 256 + threadIdx.x) >> 4);
    if (e >= E) return;

    int src, dst;
    if (e64) {
        src = (int)edge_raw[2 * (size_t)e];
        dst = (int)edge_raw[2 * ((size_t)E + e)];
    } else {
        const int* e32 = (const int*)edge_raw;
        src = e32[e];
        dst = e32[(size_t)E + e];
    }

    const f32x4 s0 = *(const f32x4*)(h + (size_t)src * N_OUT + s * 8);
    const f32x4 s1 = *(const f32x4*)(h + (size_t)src * N_OUT + s * 8 + 4);
    const f32x4 d0 = *(const f32x4*)(h + (size_t)dst * N_OUT + s * 8);
    const f32x4 d1 = *(const f32x4*)(h + (size_t)dst * N_OUT + s * 8 + 4);
    const f32x4 a0 = *(const f32x4*)(a + s * 8);
    const f32x4 a1 = *(const f32x4*)(a + s * 8 + 4);

    float sum = 0.f;
    #pragma unroll
    for (int i = 0; i < 4; ++i) sum += fabsf(s0[i] - d0[i]) * a0[i];
    #pragma unroll
    for (int i = 0; i < 4; ++i) sum += fabsf(s1[i] - d1[i]) * a1[i];

    sum += __shfl_xor(sum, 1, 64);
    sum += __shfl_xor(sum, 2, 64);
    sum += __shfl_xor(sum, 4, 64);
    sum += __shfl_xor(sum, 8, 64);

    if (s == 0) ew[e] = fmaxf(sum, 0.f);
}

extern "C" void kernel_launch(void* const* d_in, const int* in_sizes, int n_in,
                              void* d_out, int out_size, void* d_ws, size_t ws_size,
                              hipStream_t stream) {
    const float*    in   = (const float*)d_in[0];
    const uint32_t* edge = (const uint32_t*)d_in[1];
    const float*    w    = (const float*)d_in[2];
    const float*    a    = (const float*)d_in[3];

    float* h  = (float*)d_out;
    float* ew = h + (size_t)M_NODES * N_OUT;

    // ws layout: [mirror 25.6M][ctrl 12K][rec u64 12.8M] = 38.4 MB
    const size_t mirror_bytes = (size_t)M_NODES * N_OUT * sizeof(__hip_bfloat16);
    const size_t ctrl_off = mirror_bytes;
    const size_t ctrl_sz  = 12288;            // 3*NB*4 = 9384 B, padded
    const size_t rec_off  = ctrl_off + ctrl_sz;
    const size_t need     = rec_off + (size_t)N_EDGE * sizeof(u64);

    __hip_bfloat16* hmir = (ws_size >= mirror_bytes) ? (__hip_bfloat16*)d_ws : nullptr;

    if (hmir && ws_size >= need) {
        uint32_t* ctrl = (uint32_t*)((char*)d_ws + ctrl_off);
        u64*      rec  = (u64*)((char*)d_ws + rec_off);

        hipMemsetAsync(ctrl, 0, ctrl_sz, stream);
        edge_hist<<<dim3(512), dim3(256), 0, stream>>>(edge, N_EDGE, ctrl);
        bucket_prefix<<<dim3(1), dim3(64), 0, stream>>>(ctrl);
        edge_scatter<<<dim3((N_EDGE + SCATTER_CH - 1) / SCATTER_CH), dim3(256),
                       0, stream>>>(edge, N_EDGE, ctrl + 2 * NB, rec);
        gemm_h_mfma<<<dim3(512), dim3(256), 0, stream>>>(in, w, h, hmir);
        edge_compute_lds<<<dim3(NB), dim3(256), 0, stream>>>(
            hmir, rec, ctrl, a, ew);
    } else if (hmir) {
        gemm_h_mfma<<<dim3(512), dim3(256), 0, stream>>>(in, w, h, hmir);
        const int egroups = (N_EDGE + 3) / 4;
        const int eblocks = (egroups * 16 + 255) / 256;
        edge_kernel_bf16<<<dim3(eblocks), dim3(256), 0, stream>>>(
            hmir, edge, a, ew, N_EDGE);
    } else {
        gemm_h_mfma<<<dim3(512), dim3(256), 0, stream>>>(
            in, w, h, (__hip_bfloat16*)d_ws);
        const int eblocks = (N_EDGE * 16 + 255) / 256;
        edge_kernel_f32<<<dim3(eblocks), dim3(256), 0, stream>>>(
            h, edge, a, ew, N_EDGE);
    }
}

// Round 5
// 315.508 us; speedup vs baseline: 1.2240x; 1.1525x over previous
//
#include <hip/hip_runtime.h>
#include <hip/hip_bf16.h>
#include <stdint.h>

typedef __bf16 bf16x8 __attribute__((ext_vector_type(8)));
typedef float  f32x4  __attribute__((ext_vector_type(4)));

#define M_NODES 100000
#define K_IN    256
#define N_OUT   128
#define N_EDGE  1600000

// ---------------------------------------------------------------------------
// Stage 1: h[M,N] = in[M,K] @ w[K,N]. fp32 loads -> bf16 cvt -> MFMA 16x16x32.
// Writes fp32 h (nontemporal full-line stores; never re-read) to d_out and a
// bf16 mirror (plain stores; stage 2 gathers it) to d_ws.
//
// R5: one 64x128 tile per block (grid 1563, no inter-tile pipeline drains);
// B panel held as two K=128 halves (32 VGPR instead of 64); explicit 1-deep
// A prefetch (k8+1 loads issue before k8's MFMAs). ~155 VGPR est ->
// __launch_bounds__(256,3) = 12 waves/CU (vs R1's ~8).
// Fragment layouts verified in prior sessions (MFMA vs VALU byte-identical).
// ---------------------------------------------------------------------------
template <bool FULL>
__device__ __forceinline__ void gemm_tile(
    const float* __restrict__ in, const float* __restrict__ w,
    float* __restrict__ h, __hip_bfloat16* __restrict__ hmir,
    const int m0, const int lr, const int q, const int nb)
{
    f32x4 acc[4][2];
    #pragma unroll
    for (int mt = 0; mt < 4; ++mt)
        #pragma unroll
        for (int nt = 0; nt < 2; ++nt)
            acc[mt][nt] = f32x4{0.f, 0.f, 0.f, 0.f};

    auto loadA = [&](int k8, f32x4 (&A0)[4], f32x4 (&A1)[4]) {
        const int ka = k8 * 32 + q * 8;      // lane's 8 contiguous k
        #pragma unroll
        for (int mt = 0; mt < 4; ++mt) {
            const int row = m0 + mt * 16 + lr;
            if (FULL || row < M_NODES) {
                const float* ap = in + (size_t)row * K_IN + ka;
                A0[mt] = *(const f32x4*)ap;
                A1[mt] = *(const f32x4*)(ap + 4);
            } else {
                A0[mt] = f32x4{0.f, 0.f, 0.f, 0.f};
                A1[mt] = f32x4{0.f, 0.f, 0.f, 0.f};
            }
        }
    };

    f32x4 ca[4], cb[4];                      // current k8's A (fp32)
    loadA(0, ca, cb);

    #pragma unroll
    for (int half = 0; half < 2; ++half) {
        // B half-panel: bfrag[k4][nt][j] = w[(half*4+k4)*32 + q*8 + j][col]
        bf16x8 bfrag[4][2];
        #pragma unroll
        for (int k4 = 0; k4 < 4; ++k4) {
            const int ka = (half * 4 + k4) * 32 + q * 8;
            #pragma unroll
            for (int nt = 0; nt < 2; ++nt) {
                const int col = nb + nt * 16 + lr;
                #pragma unroll
                for (int j = 0; j < 8; ++j)
                    bfrag[k4][nt][j] = (__bf16)w[(size_t)(ka + j) * N_OUT + col];
            }
        }

        #pragma unroll
        for (int k4 = 0; k4 < 4; ++k4) {
            f32x4 na[4], nb_[4];             // next k8's A — issue before MFMA
            const int k8 = half * 4 + k4;
            if (k8 < 7) loadA(k8 + 1, na, nb_);

            bf16x8 af[4];
            #pragma unroll
            for (int mt = 0; mt < 4; ++mt)
                #pragma unroll
                for (int j = 0; j < 4; ++j) {
                    af[mt][j]     = (__bf16)ca[mt][j];
                    af[mt][4 + j] = (__bf16)cb[mt][j];
                }

            #pragma unroll
            for (int mt = 0; mt < 4; ++mt)
                #pragma unroll
                for (int nt = 0; nt < 2; ++nt)
                    acc[mt][nt] = __builtin_amdgcn_mfma_f32_16x16x32_bf16(
                        af[mt], bfrag[k4][nt], acc[mt][nt], 0, 0, 0);

            if (k8 < 7) {
                #pragma unroll
                for (int mt = 0; mt < 4; ++mt) { ca[mt] = na[mt]; cb[mt] = nb_[mt]; }
            }
        }
    }

    // C/D: col = lane&15, row = (lane>>4)*4 + reg
    #pragma unroll
    for (int mt = 0; mt < 4; ++mt) {
        const int rb = m0 + mt * 16 + q * 4;
        if (!FULL && rb >= M_NODES) continue; // M%4==0: rb<M => rb+3<M
        #pragma unroll
        for (int nt = 0; nt < 2; ++nt) {
            const int col = nb + nt * 16 + lr;
            #pragma unroll
            for (int r = 0; r < 4; ++r) {
                const float v = acc[mt][nt][r];
                // 16 lanes/quad x 4B = one full 64B line per row: NT is safe
                __builtin_nontemporal_store(v, h + (size_t)(rb + r) * N_OUT + col);
                // 2B/lane partial lines: plain store so L2 write-combines
                hmir[(size_t)(rb + r) * N_OUT + col] = __float2bfloat16(v);
            }
        }
    }
}

__global__ __launch_bounds__(256, 3) void gemm_h_mfma(
    const float* __restrict__ in,            // [M,K] fp32
    const float* __restrict__ w,             // [K,N] fp32
    float* __restrict__ h,                   // [M,N] fp32 (d_out)
    __hip_bfloat16* __restrict__ hmir)       // [M,N] bf16 mirror (d_ws)
{
    const int lane = threadIdx.x & 63;
    const int wave = threadIdx.x >> 6;       // 0..3
    const int nb   = wave * 32;
    const int lr   = lane & 15;              // m (A) / n (B,C) within tile
    const int q    = lane >> 4;              // quad 0..3

    const int m0 = blockIdx.x * 64;
    if (m0 + 64 <= M_NODES)
        gemm_tile<true >(in, w, h, hmir, m0, lr, q, nb);
    else
        gemm_tile<false>(in, w, h, hmir, m0, lr, q, nb);
}

// int64 edge indices < 1e5: every high word is 0. int32: odd words random.
__device__ inline int detect_i64(const uint32_t* p) {
    return __popcll(__ballot(p[2 * (threadIdx.x & 63) + 1] == 0u)) >= 60;
}

// ---------------------------------------------------------------------------
// Stage 2 (reverted to R1's proven form): 16 lanes/edge, 4 consecutive edges
// per group (vector index loads, f32x4 output store, 8 gathers in flight).
// 99 µs = 352 MB of L2 fills @ the ~3.6 TB/s fabric ceiling (57% L2 hit).
// R2-R4 established: bucketed reordering cannot beat this — prepass floor
// (~35-77 µs) exceeds the max fill savings (~37 µs) at this problem size.
// ---------------------------------------------------------------------------
__global__ __launch_bounds__(256) void edge_kernel_bf16(
    const __hip_bfloat16* __restrict__ hm,   // [M,N] bf16 mirror
    const uint32_t* __restrict__ edge_raw,   // [2,E] int64 or int32
    const float* __restrict__ a,             // [N] fp32
    float* __restrict__ ew,                  // [E] fp32 out
    int E)
{
    const int e64 = detect_i64(edge_raw);    // before any divergence/return
    const int s  = threadIdx.x & 15;
    const int g  = (int)((blockIdx.x * 256 + threadIdx.x) >> 4);
    const int e0 = g * 4;
    if (e0 >= E) return;

    const __bf16* hb = (const __bf16*)hm;
    const f32x4 a0 = *(const f32x4*)(a + s * 8);
    const f32x4 a1 = *(const f32x4*)(a + s * 8 + 4);

    if (e0 + 3 < E) {
        int srcs[4], dsts[4];
        if (e64) {
            const uint4 s01 = *(const uint4*)(edge_raw + 2 * (size_t)e0);
            const uint4 s23 = *(const uint4*)(edge_raw + 2 * (size_t)e0 + 4);
            const uint4 d01 = *(const uint4*)(edge_raw + 2 * ((size_t)E + e0));
            const uint4 d23 = *(const uint4*)(edge_raw + 2 * ((size_t)E + e0) + 4);
            srcs[0] = (int)s01.x; srcs[1] = (int)s01.z;
            srcs[2] = (int)s23.x; srcs[3] = (int)s23.z;
            dsts[0] = (int)d01.x; dsts[1] = (int)d01.z;
            dsts[2] = (int)d23.x; dsts[3] = (int)d23.z;
        } else {
            const int4 sv = *(const int4*)((const int*)edge_raw + e0);
            const int4 dv = *(const int4*)((const int*)edge_raw + (size_t)E + e0);
            srcs[0] = sv.x; srcs[1] = sv.y; srcs[2] = sv.z; srcs[3] = sv.w;
            dsts[0] = dv.x; dsts[1] = dv.y; dsts[2] = dv.z; dsts[3] = dv.w;
        }

        bf16x8 hs[4], hd[4];                 // 8 independent gathers in flight
        #pragma unroll
        for (int u = 0; u < 4; ++u) {
            hs[u] = *(const bf16x8*)(hb + (size_t)srcs[u] * N_OUT + s * 8);
            hd[u] = *(const bf16x8*)(hb + (size_t)dsts[u] * N_OUT + s * 8);
        }

        f32x4 rr;
        #pragma unroll
        for (int u = 0; u < 4; ++u) {
            float sum = 0.f;
            #pragma unroll
            for (int i = 0; i < 4; ++i)
                sum += fabsf((float)hs[u][i] - (float)hd[u][i]) * a0[i];
            #pragma unroll
            for (int i = 0; i < 4; ++i)
                sum += fabsf((float)hs[u][4 + i] - (float)hd[u][4 + i]) * a1[i];
            sum += __shfl_xor(sum, 1, 64);
            sum += __shfl_xor(sum, 2, 64);
            sum += __shfl_xor(sum, 4, 64);
            sum += __shfl_xor(sum, 8, 64);
            rr[u] = fmaxf(sum, 0.f);
        }
        if (s == 0) *(f32x4*)(ew + e0) = rr;
    } else {
        // tail (E not a multiple of 4): per-edge scalar path
        for (int e = e0; e < E; ++e) {
            int src, dst;
            if (e64) {
                src = (int)edge_raw[2 * (size_t)e];
                dst = (int)edge_raw[2 * ((size_t)E + e)];
            } else {
                const int* e32 = (const int*)edge_raw;
                src = e32[e];
                dst = e32[(size_t)E + e];
            }
            const bf16x8 hs = *(const bf16x8*)(hb + (size_t)src * N_OUT + s * 8);
            const bf16x8 hd = *(const bf16x8*)(hb + (size_t)dst * N_OUT + s * 8);
            float sum = 0.f;
            #pragma unroll
            for (int i = 0; i < 4; ++i)
                sum += fabsf((float)hs[i] - (float)hd[i]) * a0[i];
            #pragma unroll
            for (int i = 0; i < 4; ++i)
                sum += fabsf((float)hs[4 + i] - (float)hd[4 + i]) * a1[i];
            sum += __shfl_xor(sum, 1, 64);
            sum += __shfl_xor(sum, 2, 64);
            sum += __shfl_xor(sum, 4, 64);
            sum += __shfl_xor(sum, 8, 64);
            if (s == 0) ew[e] = fmaxf(sum, 0.f);
        }
    }
}

// fp32 fallback when d_ws can't hold the mirror.
__global__ __launch_bounds__(256) void edge_kernel_f32(
    const float* __restrict__ h,
    const uint32_t* __restrict__ edge_raw,
    const float* __restrict__ a,
    float* __restrict__ ew,
    int E)
{
    const int e64 = detect_i64(edge_raw);
    const int s = threadIdx.x & 15;
    const int e = (int)((blockIdx.x * 256 + threadIdx.x) >> 4);
    if (e >= E) return;

    int src, dst;
    if (e64) {
        src = (int)edge_raw[2 * (size_t)e];
        dst = (int)edge_raw[2 * ((size_t)E + e)];
    } else {
        const int* e32 = (const int*)edge_raw;
        src = e32[e];
        dst = e32[(size_t)E + e];
    }

    const f32x4 s0 = *(const f32x4*)(h + (size_t)src * N_OUT + s * 8);
    const f32x4 s1 = *(const f32x4*)(h + (size_t)src * N_OUT + s * 8 + 4);
    const f32x4 d0 = *(const f32x4*)(h + (size_t)dst * N_OUT + s * 8);
    const f32x4 d1 = *(const f32x4*)(h + (size_t)dst * N_OUT + s * 8 + 4);
    const f32x4 a0 = *(const f32x4*)(a + s * 8);
    const f32x4 a1 = *(const f32x4*)(a + s * 8 + 4);

    float sum = 0.f;
    #pragma unroll
    for (int i = 0; i < 4; ++i) sum += fabsf(s0[i] - d0[i]) * a0[i];
    #pragma unroll
    for (int i = 0; i < 4; ++i) sum += fabsf(s1[i] - d1[i]) * a1[i];

    sum += __shfl_xor(sum, 1, 64);
    sum += __shfl_xor(sum, 2, 64);
    sum += __shfl_xor(sum, 4, 64);
    sum += __shfl_xor(sum, 8, 64);

    if (s == 0) ew[e] = fmaxf(sum, 0.f);
}

extern "C" void kernel_launch(void* const* d_in, const int* in_sizes, int n_in,
                              void* d_out, int out_size, void* d_ws, size_t ws_size,
                              hipStream_t stream) {
    // d_in = { inputs fp32[100000,256], edge int64[2,E], weight fp32[256,128],
    //          a fp32[128,1] }   (documented dict order — validated R0-R6)
    // d_out = fp32: h[100000,128] then edge_weight[E].
    const float*    in   = (const float*)d_in[0];
    const uint32_t* edge = (const uint32_t*)d_in[1];
    const float*    w    = (const float*)d_in[2];
    const float*    a    = (const float*)d_in[3];

    float* h  = (float*)d_out;
    float* ew = h + (size_t)M_NODES * N_OUT;

    const size_t mirror_bytes = (size_t)M_NODES * N_OUT * sizeof(__hip_bfloat16);
    __hip_bfloat16* hmir =
        (ws_size >= mirror_bytes) ? (__hip_bfloat16*)d_ws : nullptr;

    const int gblocks = (M_NODES + 63) / 64;             // 1563, 1 tile/block

    if (hmir) {
        gemm_h_mfma<<<dim3(gblocks), dim3(256), 0, stream>>>(in, w, h, hmir);
        const int egroups = (N_EDGE + 3) / 4;            // 4 edges / 16 lanes
        const int eblocks = (egroups * 16 + 255) / 256;  // 25000
        edge_kernel_bf16<<<dim3(eblocks), dim3(256), 0, stream>>>(
            hmir, edge, a, ew, N_EDGE);
    } else {
        gemm_h_mfma<<<dim3(gblocks), dim3(256), 0, stream>>>(
            in, w, h, (__hip_bfloat16*)d_ws);  // unreachable in practice
        const int eblocks = (N_EDGE * 16 + 255) / 256;
        edge_kernel_f32<<<dim3(eblocks), dim3(256), 0, stream>>>(
            h, edge, a, ew, N_EDGE);
    }
}

// Round 6
// 302.589 us; speedup vs baseline: 1.2762x; 1.0427x over previous
//
#include <hip/hip_runtime.h>
#include <hip/hip_bf16.h>
#include <stdint.h>

typedef __bf16 bf16x8 __attribute__((ext_vector_type(8)));
typedef float  f32x4  __attribute__((ext_vector_type(4)));

#define M_NODES 100000
#define K_IN    256
#define N_OUT   128
#define N_EDGE  1600000

// ---------------------------------------------------------------------------
// Stage 1: h[M,N] = in[M,K] @ w[K,N]. fp32 loads -> bf16 cvt -> MFMA
// 16x16x32 (fp32 accum). Writes fp32 h (nontemporal; never re-read) to d_out
// and a bf16 mirror (cached; stage 2 gathers it) to d_ws.
//
// R6: REVERTED to R1's proven structure (best measured: non-edge ~200 µs).
// R5's 1-tile/block + prefetch + launch_bounds(256,3) regressed ~17 µs
// (likely VGPR spill under the forced bound + 3x B-panel reload traffic).
// ---------------------------------------------------------------------------
template <bool FULL>
__device__ __forceinline__ void gemm_tile(
    const float* __restrict__ in, float* __restrict__ h,
    __hip_bfloat16* __restrict__ hmir,
    const bf16x8 (&bfrag)[8][2], const int m0, const int lr, const int q,
    const int nb)
{
    f32x4 acc[4][2];
    #pragma unroll
    for (int mt = 0; mt < 4; ++mt)
        #pragma unroll
        for (int nt = 0; nt < 2; ++nt)
            acc[mt][nt] = f32x4{0.f, 0.f, 0.f, 0.f};

    #pragma unroll
    for (int k8 = 0; k8 < 8; ++k8) {
        const int ka = k8 * 32 + q * 8;      // lane's 8 contiguous k
        bf16x8 afrag[4];                     // A[m=lr][k=ka..ka+7]
        #pragma unroll
        for (int mt = 0; mt < 4; ++mt) {
            const int row = m0 + mt * 16 + lr;
            if (FULL || row < M_NODES) {
                const float* ap = in + (size_t)row * K_IN + ka;
                const f32x4 a0 = *(const f32x4*)ap;
                const f32x4 a1 = *(const f32x4*)(ap + 4);
                #pragma unroll
                for (int j = 0; j < 4; ++j) {
                    afrag[mt][j]     = (__bf16)a0[j];
                    afrag[mt][4 + j] = (__bf16)a1[j];
                }
            } else {
                #pragma unroll
                for (int j = 0; j < 8; ++j) afrag[mt][j] = (__bf16)0.f;
            }
        }
        #pragma unroll
        for (int mt = 0; mt < 4; ++mt)
            #pragma unroll
            for (int nt = 0; nt < 2; ++nt)
                acc[mt][nt] = __builtin_amdgcn_mfma_f32_16x16x32_bf16(
                    afrag[mt], bfrag[k8][nt], acc[mt][nt], 0, 0, 0);
    }

    // C/D: col = lane&15, row = (lane>>4)*4 + reg
    #pragma unroll
    for (int mt = 0; mt < 4; ++mt) {
        const int rb = m0 + mt * 16 + q * 4;
        if (!FULL && rb >= M_NODES) continue; // M%4==0: rb<M => rb+3<M
        #pragma unroll
        for (int nt = 0; nt < 2; ++nt) {
            const int col = nb + nt * 16 + lr;
            #pragma unroll
            for (int r = 0; r < 4; ++r) {
                const float v = acc[mt][nt][r];
                __builtin_nontemporal_store(v, h + (size_t)(rb + r) * N_OUT + col);
                hmir[(size_t)(rb + r) * N_OUT + col] = __float2bfloat16(v);
            }
        }
    }
}

__global__ __launch_bounds__(256) void gemm_h_mfma(
    const float* __restrict__ in,            // [M,K] fp32
    const float* __restrict__ w,             // [K,N] fp32
    float* __restrict__ h,                   // [M,N] fp32 (d_out)
    __hip_bfloat16* __restrict__ hmir)       // [M,N] bf16 mirror (d_ws)
{
    const int lane = threadIdx.x & 63;
    const int wave = threadIdx.x >> 6;       // 0..3
    const int nb   = wave * 32;
    const int lr   = lane & 15;              // m (A) / n (B,C) within tile
    const int q    = lane >> 4;              // quad 0..3

    // Preload the wave's full B panel: bfrag[k8][nt][j] = w[k8*32+q*8+j][nb+nt*16+lr]
    bf16x8 bfrag[8][2];
    #pragma unroll
    for (int k8 = 0; k8 < 8; ++k8) {
        const int ka = k8 * 32 + q * 8;
        #pragma unroll
        for (int nt = 0; nt < 2; ++nt) {
            const int col = nb + nt * 16 + lr;
            #pragma unroll
            for (int j = 0; j < 8; ++j)
                bfrag[k8][nt][j] = (__bf16)w[(size_t)(ka + j) * N_OUT + col];
        }
    }

    const int ntiles = (M_NODES + 63) / 64;  // 1563
    const int nfull  = M_NODES / 64;         // 1562 guard-free tiles
    for (int t = blockIdx.x; t < ntiles; t += gridDim.x) {
        const int m0 = t * 64;
        if (t < nfull) gemm_tile<true >(in, h, hmir, bfrag, m0, lr, q, nb);
        else           gemm_tile<false>(in, h, hmir, bfrag, m0, lr, q, nb);
    }
}

// int64 edge indices < 1e5: every high word is 0. int32: odd words random.
__device__ inline int detect_i64(const uint32_t* p) {
    return __popcll(__ballot(p[2 * (threadIdx.x & 63) + 1] == 0u)) >= 60;
}

// ---------------------------------------------------------------------------
// Stage 2 (R1's proven form; 98 µs = 344 MB L2-miss fill @ ~3.6 TB/s fabric
// ceiling). R6: launched TWICE over [e_base, e_end) halves so GEMM can enter
// the profiler's top-5 (pure visibility split; same total gather work).
// R2-R4 established bucketed reordering is net-negative at this size.
// ---------------------------------------------------------------------------
__global__ __launch_bounds__(256) void edge_kernel_bf16(
    const __hip_bfloat16* __restrict__ hm,   // [M,N] bf16 mirror
    const uint32_t* __restrict__ edge_raw,   // [2,E] int64 or int32
    const float* __restrict__ a,             // [N] fp32
    float* __restrict__ ew,                  // [E] fp32 out
    int E,                                   // total edge count (array stride)
    int e_base, int e_end)                   // this launch's range
{
    const int e64 = detect_i64(edge_raw);    // before any divergence/return
    const int s  = threadIdx.x & 15;
    const int g  = (int)((blockIdx.x * 256 + threadIdx.x) >> 4);
    const int e0 = e_base + g * 4;
    if (e0 >= e_end) return;

    const __bf16* hb = (const __bf16*)hm;
    const f32x4 a0 = *(const f32x4*)(a + s * 8);
    const f32x4 a1 = *(const f32x4*)(a + s * 8 + 4);

    if (e0 + 3 < e_end) {
        int srcs[4], dsts[4];
        if (e64) {
            const uint4 s01 = *(const uint4*)(edge_raw + 2 * (size_t)e0);
            const uint4 s23 = *(const uint4*)(edge_raw + 2 * (size_t)e0 + 4);
            const uint4 d01 = *(const uint4*)(edge_raw + 2 * ((size_t)E + e0));
            const uint4 d23 = *(const uint4*)(edge_raw + 2 * ((size_t)E + e0) + 4);
            srcs[0] = (int)s01.x; srcs[1] = (int)s01.z;
            srcs[2] = (int)s23.x; srcs[3] = (int)s23.z;
            dsts[0] = (int)d01.x; dsts[1] = (int)d01.z;
            dsts[2] = (int)d23.x; dsts[3] = (int)d23.z;
        } else {
            const int4 sv = *(const int4*)((const int*)edge_raw + e0);
            const int4 dv = *(const int4*)((const int*)edge_raw + (size_t)E + e0);
            srcs[0] = sv.x; srcs[1] = sv.y; srcs[2] = sv.z; srcs[3] = sv.w;
            dsts[0] = dv.x; dsts[1] = dv.y; dsts[2] = dv.z; dsts[3] = dv.w;
        }

        bf16x8 hs[4], hd[4];                 // 8 independent gathers in flight
        #pragma unroll
        for (int u = 0; u < 4; ++u) {
            hs[u] = *(const bf16x8*)(hb + (size_t)srcs[u] * N_OUT + s * 8);
            hd[u] = *(const bf16x8*)(hb + (size_t)dsts[u] * N_OUT + s * 8);
        }

        f32x4 rr;
        #pragma unroll
        for (int u = 0; u < 4; ++u) {
            float sum = 0.f;
            #pragma unroll
            for (int i = 0; i < 4; ++i)
                sum += fabsf((float)hs[u][i] - (float)hd[u][i]) * a0[i];
            #pragma unroll
            for (int i = 0; i < 4; ++i)
                sum += fabsf((float)hs[u][4 + i] - (float)hd[u][4 + i]) * a1[i];
            sum += __shfl_xor(sum, 1, 64);
            sum += __shfl_xor(sum, 2, 64);
            sum += __shfl_xor(sum, 4, 64);
            sum += __shfl_xor(sum, 8, 64);
            rr[u] = fmaxf(sum, 0.f);
        }
        if (s == 0) *(f32x4*)(ew + e0) = rr;
    } else {
        // tail (range not a multiple of 4): per-edge scalar path
        for (int e = e0; e < e_end; ++e) {
            int src, dst;
            if (e64) {
                src = (int)edge_raw[2 * (size_t)e];
                dst = (int)edge_raw[2 * ((size_t)E + e)];
            } else {
                const int* e32 = (const int*)edge_raw;
                src = e32[e];
                dst = e32[(size_t)E + e];
            }
            const bf16x8 hs = *(const bf16x8*)(hb + (size_t)src * N_OUT + s * 8);
            const bf16x8 hd = *(const bf16x8*)(hb + (size_t)dst * N_OUT + s * 8);
            float sum = 0.f;
            #pragma unroll
            for (int i = 0; i < 4; ++i)
                sum += fabsf((float)hs[i] - (float)hd[i]) * a0[i];
            #pragma unroll
            for (int i = 0; i < 4; ++i)
                sum += fabsf((float)hs[4 + i] - (float)hd[4 + i]) * a1[i];
            sum += __shfl_xor(sum, 1, 64);
            sum += __shfl_xor(sum, 2, 64);
            sum += __shfl_xor(sum, 4, 64);
            sum += __shfl_xor(sum, 8, 64);
            if (s == 0) ew[e] = fmaxf(sum, 0.f);
        }
    }
}

// fp32 fallback when d_ws can't hold the mirror.
__global__ __launch_bounds__(256) void edge_kernel_f32(
    const float* __restrict__ h,
    const uint32_t* __restrict__ edge_raw,
    const float* __restrict__ a,
    float* __restrict__ ew,
    int E)
{
    const int e64 = detect_i64(edge_raw);
    const int s = threadIdx.x & 15;
    const int e = (int)((blockIdx.x * 256 + threadIdx.x) >> 4);
    if (e >= E) return;

    int src, dst;
    if (e64) {
        src = (int)edge_raw[2 * (size_t)e];
        dst = (int)edge_raw[2 * ((size_t)E + e)];
    } else {
        const int* e32 = (const int*)edge_raw;
        src = e32[e];
        dst = e32[(size_t)E + e];
    }

    const f32x4 s0 = *(const f32x4*)(h + (size_t)src * N_OUT + s * 8);
    const f32x4 s1 = *(const f32x4*)(h + (size_t)src * N_OUT + s * 8 + 4);
    const f32x4 d0 = *(const f32x4*)(h + (size_t)dst * N_OUT + s * 8);
    const f32x4 d1 = *(const f32x4*)(h + (size_t)dst * N_OUT + s * 8 + 4);
    const f32x4 a0 = *(const f32x4*)(a + s * 8);
    const f32x4 a1 = *(const f32x4*)(a + s * 8 + 4);

    float sum = 0.f;
    #pragma unroll
    for (int i = 0; i < 4; ++i) sum += fabsf(s0[i] - d0[i]) * a0[i];
    #pragma unroll
    for (int i = 0; i < 4; ++i) sum += fabsf(s1[i] - d1[i]) * a1[i];

    sum += __shfl_xor(sum, 1, 64);
    sum += __shfl_xor(sum, 2, 64);
    sum += __shfl_xor(sum, 4, 64);
    sum += __shfl_xor(sum, 8, 64);

    if (s == 0) ew[e] = fmaxf(sum, 0.f);
}

extern "C" void kernel_launch(void* const* d_in, const int* in_sizes, int n_in,
                              void* d_out, int out_size, void* d_ws, size_t ws_size,
                              hipStream_t stream) {
    // d_in = { inputs fp32[100000,256], edge int64[2,E], weight fp32[256,128],
    //          a fp32[128,1] }   (documented dict order — validated R0-R6)
    // d_out = fp32: h[100000,128] then edge_weight[E].
    const float*    in   = (const float*)d_in[0];
    const uint32_t* edge = (const uint32_t*)d_in[1];
    const float*    w    = (const float*)d_in[2];
    const float*    a    = (const float*)d_in[3];

    float* h  = (float*)d_out;
    float* ew = h + (size_t)M_NODES * N_OUT;

    const size_t mirror_bytes = (size_t)M_NODES * N_OUT * sizeof(__hip_bfloat16);
    __hip_bfloat16* hmir =
        (ws_size >= mirror_bytes) ? (__hip_bfloat16*)d_ws : nullptr;

    if (hmir) {
        // grid=512: 2 blocks/CU, ~3 row-tiles/block amortize B-panel preload.
        gemm_h_mfma<<<dim3(512), dim3(256), 0, stream>>>(in, w, h, hmir);
        // Edge split into two half-range launches (~49 µs each) so the GEMM
        // dispatch can surface in rocprof's top-5 (visibility; same work).
        const int eh = N_EDGE / 2;                        // 800000, %4 == 0
        const int eblocks = (eh / 4 * 16 + 255) / 256;    // 12500
        edge_kernel_bf16<<<dim3(eblocks), dim3(256), 0, stream>>>(
            hmir, edge, a, ew, N_EDGE, 0, eh);
        edge_kernel_bf16<<<dim3(eblocks), dim3(256), 0, stream>>>(
            hmir, edge, a, ew, N_EDGE, eh, N_EDGE);
    } else {
        gemm_h_mfma<<<dim3(512), dim3(256), 0, stream>>>(
            in, w, h, (__hip_bfloat16*)d_ws);  // unreachable in practice
        const int eblocks = (N_EDGE * 16 + 255) / 256;
        edge_kernel_f32<<<dim3(eblocks), dim3(256), 0, stream>>>(
            h, edge, a, ew, N_EDGE);
    }
}

// Round 7
// 301.351 us; speedup vs baseline: 1.2815x; 1.0041x over previous
//
#include <hip/hip_runtime.h>
#include <hip/hip_bf16.h>
#include <stdint.h>

typedef __bf16 bf16x8 __attribute__((ext_vector_type(8)));
typedef float  f32x4  __attribute__((ext_vector_type(4)));

#define M_NODES 100000
#define K_IN    256
#define N_OUT   128
#define N_EDGE  1600000

// ---------------------------------------------------------------------------
// Stage 1: h[M,N] = in[M,K] @ w[K,N]. fp32 loads -> bf16 cvt -> MFMA
// 16x16x32 (fp32 accum). Writes fp32 h (nontemporal; never re-read) to d_out
// and a bf16 mirror (cached; stage 2 gathers it) to d_ws.
//
// R7: structure unchanged from R1/R6 (best measured). ONLY change: grid
// 512 -> 1024. R6 counters showed Occupancy 17% / VALUBusy 5.8% / MfmaUtil
// 3.1% — pure latency starvation with grid (2 blocks/CU), not VGPR(120),
// as the residency cap. 1024 blocks = 4 blocks/CU = 4 waves/SIMD = the
// VGPR limit. R5's lesson: do NOT add launch_bounds min or prefetch.
// ---------------------------------------------------------------------------
template <bool FULL>
__device__ __forceinline__ void gemm_tile(
    const float* __restrict__ in, float* __restrict__ h,
    __hip_bfloat16* __restrict__ hmir,
    const bf16x8 (&bfrag)[8][2], const int m0, const int lr, const int q,
    const int nb)
{
    f32x4 acc[4][2];
    #pragma unroll
    for (int mt = 0; mt < 4; ++mt)
        #pragma unroll
        for (int nt = 0; nt < 2; ++nt)
            acc[mt][nt] = f32x4{0.f, 0.f, 0.f, 0.f};

    #pragma unroll
    for (int k8 = 0; k8 < 8; ++k8) {
        const int ka = k8 * 32 + q * 8;      // lane's 8 contiguous k
        bf16x8 afrag[4];                     // A[m=lr][k=ka..ka+7]
        #pragma unroll
        for (int mt = 0; mt < 4; ++mt) {
            const int row = m0 + mt * 16 + lr;
            if (FULL || row < M_NODES) {
                const float* ap = in + (size_t)row * K_IN + ka;
                const f32x4 a0 = *(const f32x4*)ap;
                const f32x4 a1 = *(const f32x4*)(ap + 4);
                #pragma unroll
                for (int j = 0; j < 4; ++j) {
                    afrag[mt][j]     = (__bf16)a0[j];
                    afrag[mt][4 + j] = (__bf16)a1[j];
                }
            } else {
                #pragma unroll
                for (int j = 0; j < 8; ++j) afrag[mt][j] = (__bf16)0.f;
            }
        }
        #pragma unroll
        for (int mt = 0; mt < 4; ++mt)
            #pragma unroll
            for (int nt = 0; nt < 2; ++nt)
                acc[mt][nt] = __builtin_amdgcn_mfma_f32_16x16x32_bf16(
                    afrag[mt], bfrag[k8][nt], acc[mt][nt], 0, 0, 0);
    }

    // C/D: col = lane&15, row = (lane>>4)*4 + reg
    #pragma unroll
    for (int mt = 0; mt < 4; ++mt) {
        const int rb = m0 + mt * 16 + q * 4;
        if (!FULL && rb >= M_NODES) continue; // M%4==0: rb<M => rb+3<M
        #pragma unroll
        for (int nt = 0; nt < 2; ++nt) {
            const int col = nb + nt * 16 + lr;
            #pragma unroll
            for (int r = 0; r < 4; ++r) {
                const float v = acc[mt][nt][r];
                __builtin_nontemporal_store(v, h + (size_t)(rb + r) * N_OUT + col);
                hmir[(size_t)(rb + r) * N_OUT + col] = __float2bfloat16(v);
            }
        }
    }
}

__global__ __launch_bounds__(256) void gemm_h_mfma(
    const float* __restrict__ in,            // [M,K] fp32
    const float* __restrict__ w,             // [K,N] fp32
    float* __restrict__ h,                   // [M,N] fp32 (d_out)
    __hip_bfloat16* __restrict__ hmir)       // [M,N] bf16 mirror (d_ws)
{
    const int lane = threadIdx.x & 63;
    const int wave = threadIdx.x >> 6;       // 0..3
    const int nb   = wave * 32;
    const int lr   = lane & 15;              // m (A) / n (B,C) within tile
    const int q    = lane >> 4;              // quad 0..3

    // Preload the wave's full B panel: bfrag[k8][nt][j] = w[k8*32+q*8+j][nb+nt*16+lr]
    bf16x8 bfrag[8][2];
    #pragma unroll
    for (int k8 = 0; k8 < 8; ++k8) {
        const int ka = k8 * 32 + q * 8;
        #pragma unroll
        for (int nt = 0; nt < 2; ++nt) {
            const int col = nb + nt * 16 + lr;
            #pragma unroll
            for (int j = 0; j < 8; ++j)
                bfrag[k8][nt][j] = (__bf16)w[(size_t)(ka + j) * N_OUT + col];
        }
    }

    const int ntiles = (M_NODES + 63) / 64;  // 1563
    const int nfull  = M_NODES / 64;         // 1562 guard-free tiles
    for (int t = blockIdx.x; t < ntiles; t += gridDim.x) {
        const int m0 = t * 64;
        if (t < nfull) gemm_tile<true >(in, h, hmir, bfrag, m0, lr, q, nb);
        else           gemm_tile<false>(in, h, hmir, bfrag, m0, lr, q, nb);
    }
}

// int64 edge indices < 1e5: every high word is 0. int32: odd words random.
__device__ inline int detect_i64(const uint32_t* p) {
    return __popcll(__ballot(p[2 * (threadIdx.x & 63) + 1] == 0u)) >= 60;
}

// ---------------------------------------------------------------------------
// Stage 2 (R1's proven form, single launch): 16 lanes/edge, 4 consecutive
// edges per group. 98 µs = 344 MB of L2-miss fill @ the ~3.6 TB/s fabric
// ceiling (58% L2 hit on the 25.6 MB mirror). R2-R4 established bucketed
// reordering is net-negative at this size (prepass floor > fill savings).
// ---------------------------------------------------------------------------
__global__ __launch_bounds__(256) void edge_kernel_bf16(
    const __hip_bfloat16* __restrict__ hm,   // [M,N] bf16 mirror
    const uint32_t* __restrict__ edge_raw,   // [2,E] int64 or int32
    const float* __restrict__ a,             // [N] fp32
    float* __restrict__ ew,                  // [E] fp32 out
    int E)
{
    const int e64 = detect_i64(edge_raw);    // before any divergence/return
    const int s  = threadIdx.x & 15;
    const int g  = (int)((blockIdx.x * 256 + threadIdx.x) >> 4);
    const int e0 = g * 4;
    if (e0 >= E) return;

    const __bf16* hb = (const __bf16*)hm;
    const f32x4 a0 = *(const f32x4*)(a + s * 8);
    const f32x4 a1 = *(const f32x4*)(a + s * 8 + 4);

    if (e0 + 3 < E) {
        int srcs[4], dsts[4];
        if (e64) {
            const uint4 s01 = *(const uint4*)(edge_raw + 2 * (size_t)e0);
            const uint4 s23 = *(const uint4*)(edge_raw + 2 * (size_t)e0 + 4);
            const uint4 d01 = *(const uint4*)(edge_raw + 2 * ((size_t)E + e0));
            const uint4 d23 = *(const uint4*)(edge_raw + 2 * ((size_t)E + e0) + 4);
            srcs[0] = (int)s01.x; srcs[1] = (int)s01.z;
            srcs[2] = (int)s23.x; srcs[3] = (int)s23.z;
            dsts[0] = (int)d01.x; dsts[1] = (int)d01.z;
            dsts[2] = (int)d23.x; dsts[3] = (int)d23.z;
        } else {
            const int4 sv = *(const int4*)((const int*)edge_raw + e0);
            const int4 dv = *(const int4*)((const int*)edge_raw + (size_t)E + e0);
            srcs[0] = sv.x; srcs[1] = sv.y; srcs[2] = sv.z; srcs[3] = sv.w;
            dsts[0] = dv.x; dsts[1] = dv.y; dsts[2] = dv.z; dsts[3] = dv.w;
        }

        bf16x8 hs[4], hd[4];                 // 8 independent gathers in flight
        #pragma unroll
        for (int u = 0; u < 4; ++u) {
            hs[u] = *(const bf16x8*)(hb + (size_t)srcs[u] * N_OUT + s * 8);
            hd[u] = *(const bf16x8*)(hb + (size_t)dsts[u] * N_OUT + s * 8);
        }

        f32x4 rr;
        #pragma unroll
        for (int u = 0; u < 4; ++u) {
            float sum = 0.f;
            #pragma unroll
            for (int i = 0; i < 4; ++i)
                sum += fabsf((float)hs[u][i] - (float)hd[u][i]) * a0[i];
            #pragma unroll
            for (int i = 0; i < 4; ++i)
                sum += fabsf((float)hs[u][4 + i] - (float)hd[u][4 + i]) * a1[i];
            sum += __shfl_xor(sum, 1, 64);
            sum += __shfl_xor(sum, 2, 64);
            sum += __shfl_xor(sum, 4, 64);
            sum += __shfl_xor(sum, 8, 64);
            rr[u] = fmaxf(sum, 0.f);
        }
        if (s == 0) *(f32x4*)(ew + e0) = rr;
    } else {
        // tail (E not a multiple of 4): per-edge scalar path
        for (int e = e0; e < E; ++e) {
            int src, dst;
            if (e64) {
                src = (int)edge_raw[2 * (size_t)e];
                dst = (int)edge_raw[2 * ((size_t)E + e)];
            } else {
                const int* e32 = (const int*)edge_raw;
                src = e32[e];
                dst = e32[(size_t)E + e];
            }
            const bf16x8 hs = *(const bf16x8*)(hb + (size_t)src * N_OUT + s * 8);
            const bf16x8 hd = *(const bf16x8*)(hb + (size_t)dst * N_OUT + s * 8);
            float sum = 0.f;
            #pragma unroll
            for (int i = 0; i < 4; ++i)
                sum += fabsf((float)hs[i] - (float)hd[i]) * a0[i];
            #pragma unroll
            for (int i = 0; i < 4; ++i)
                sum += fabsf((float)hs[4 + i] - (float)hd[4 + i]) * a1[i];
            sum += __shfl_xor(sum, 1, 64);
            sum += __shfl_xor(sum, 2, 64);
            sum += __shfl_xor(sum, 4, 64);
            sum += __shfl_xor(sum, 8, 64);
            if (s == 0) ew[e] = fmaxf(sum, 0.f);
        }
    }
}

// fp32 fallback when d_ws can't hold the mirror.
__global__ __launch_bounds__(256) void edge_kernel_f32(
    const float* __restrict__ h,
    const uint32_t* __restrict__ edge_raw,
    const float* __restrict__ a,
    float* __restrict__ ew,
    int E)
{
    const int e64 = detect_i64(edge_raw);
    const int s = threadIdx.x & 15;
    const int e = (int)((blockIdx.x * 256 + threadIdx.x) >> 4);
    if (e >= E) return;

    int src, dst;
    if (e64) {
        src = (int)edge_raw[2 * (size_t)e];
        dst = (int)edge_raw[2 * ((size_t)E + e)];
    } else {
        const int* e32 = (const int*)edge_raw;
        src = e32[e];
        dst = e32[(size_t)E + e];
    }

    const f32x4 s0 = *(const f32x4*)(h + (size_t)src * N_OUT + s * 8);
    const f32x4 s1 = *(const f32x4*)(h + (size_t)src * N_OUT + s * 8 + 4);
    const f32x4 d0 = *(const f32x4*)(h + (size_t)dst * N_OUT + s * 8);
    const f32x4 d1 = *(const f32x4*)(h + (size_t)dst * N_OUT + s * 8 + 4);
    const f32x4 a0 = *(const f32x4*)(a + s * 8);
    const f32x4 a1 = *(const f32x4*)(a + s * 8 + 4);

    float sum = 0.f;
    #pragma unroll
    for (int i = 0; i < 4; ++i) sum += fabsf(s0[i] - d0[i]) * a0[i];
    #pragma unroll
    for (int i = 0; i < 4; ++i) sum += fabsf(s1[i] - d1[i]) * a1[i];

    sum += __shfl_xor(sum, 1, 64);
    sum += __shfl_xor(sum, 2, 64);
    sum += __shfl_xor(sum, 4, 64);
    sum += __shfl_xor(sum, 8, 64);

    if (s == 0) ew[e] = fmaxf(sum, 0.f);
}

extern "C" void kernel_launch(void* const* d_in, const int* in_sizes, int n_in,
                              void* d_out, int out_size, void* d_ws, size_t ws_size,
                              hipStream_t stream) {
    // d_in = { inputs fp32[100000,256], edge int64[2,E], weight fp32[256,128],
    //          a fp32[128,1] }   (documented dict order — validated R0-R6)
    // d_out = fp32: h[100000,128] then edge_weight[E].
    const float*    in   = (const float*)d_in[0];
    const uint32_t* edge = (const uint32_t*)d_in[1];
    const float*    w    = (const float*)d_in[2];
    const float*    a    = (const float*)d_in[3];

    float* h  = (float*)d_out;
    float* ew = h + (size_t)M_NODES * N_OUT;

    const size_t mirror_bytes = (size_t)M_NODES * N_OUT * sizeof(__hip_bfloat16);
    __hip_bfloat16* hmir =
        (ws_size >= mirror_bytes) ? (__hip_bfloat16*)d_ws : nullptr;

    if (hmir) {
        // grid=1024: 4 blocks/CU = 4 waves/SIMD (the VGPR-120 cap).
        // R6 @ grid 512 measured Occupancy 17% / VALUBusy 5.8% — grid-capped.
        gemm_h_mfma<<<dim3(1024), dim3(256), 0, stream>>>(in, w, h, hmir);
        const int egroups = (N_EDGE + 3) / 4;            // 4 edges / 16 lanes
        const int eblocks = (egroups * 16 + 255) / 256;  // 25000
        edge_kernel_bf16<<<dim3(eblocks), dim3(256), 0, stream>>>(
            hmir, edge, a, ew, N_EDGE);
    } else {
        gemm_h_mfma<<<dim3(1024), dim3(256), 0, stream>>>(
            in, w, h, (__hip_bfloat16*)d_ws);  // unreachable in practice
        const int eblocks = (N_EDGE * 16 + 255) / 256;
        edge_kernel_f32<<<dim3(eblocks), dim3(256), 0, stream>>>(
            h, edge, a, ew, N_EDGE);
    }
}